// Round 7
// baseline (87282.007 us; speedup 1.0000x reference)
//
#include <hip/hip_runtime.h>
#include <cstdint>
#include <cstddef>

#define DEV static __device__ __forceinline__

DEV float wredf(float v) {
  v += __shfl_xor(v, 32, 64); v += __shfl_xor(v, 16, 64);
  v += __shfl_xor(v, 8, 64);  v += __shfl_xor(v, 4, 64);
  v += __shfl_xor(v, 2, 64);  v += __shfl_xor(v, 1, 64);
  return v;
}

// ---- embed: src = [x,t] @ emb_W + emb_b  (fp32) --------------------------
__global__ __launch_bounds__(256)
void embed_kernel(const float* __restrict__ x, const float* __restrict__ t,
                  const float* __restrict__ W, const float* __restrict__ eb,
                  float* __restrict__ X) {
  const int gid = blockIdx.x * 256 + threadIdx.x;  // R*64
  const int row = gid >> 6, d = (gid & 63) * 8;
  const float xv = x[row], tv = t[row];
  #pragma unroll
  for (int j = 0; j < 8; j++)
    X[(size_t)row * 512 + d + j] =
        xv * W[d + j] + tv * W[512 + d + j] + eb[d + j];
}

// ---- layernorm row=512, fp32 -> fp32, one wave per row -------------------
__global__ __launch_bounds__(256)
void ln_kernel(const float* __restrict__ X, const float* __restrict__ w,
               const float* __restrict__ bb, float* __restrict__ out) {
  const int row = blockIdx.x * 4 + (threadIdx.x >> 6);
  const int lane = threadIdx.x & 63;
  const float* xp = X + (size_t)row * 512 + lane * 8;
  float4 a0 = *(const float4*)xp;
  float4 a1 = *(const float4*)(xp + 4);
  float v[8] = {a0.x, a0.y, a0.z, a0.w, a1.x, a1.y, a1.z, a1.w};
  float s = 0.f, sq = 0.f;
  #pragma unroll
  for (int j = 0; j < 8; j++) { s += v[j]; sq += v[j] * v[j]; }
  s = wredf(s); sq = wredf(sq);
  const float mean = s * (1.f / 512.f);
  const float var = fmaxf(sq * (1.f / 512.f) - mean * mean, 0.f);
  const float inv = rsqrtf(var + 1e-5f);
  const float* wp = w + lane * 8;
  const float* bp = bb + lane * 8;
  float* op = out + (size_t)row * 512 + lane * 8;
  #pragma unroll
  for (int j = 0; j < 8; j++)
    op[j] = (v[j] - mean) * inv * wp[j] + bp[j];
}

// ---- xpos rotation on Q,K inside QKV buffer (row x 2048 fp32) ------------
__global__ __launch_bounds__(256)
void xpos_kernel(float* __restrict__ QKV) {
  const int gid = blockIdx.x * 256 + threadIdx.x;  // R*256
  const int row = gid >> 8, r = gid & 255;
  const int h = r >> 5, i = r & 31;
  const int s = row & 255;
  const float sv = (2.0f * i + 0.4f * 64.0f) / (1.4f * 64.0f);
  const float sc = powf(sv, (float)s / 512.0f);
  const float isc = 1.0f / sc;
  const float invf = powf(10000.0f, -((float)i) / 32.0f);
  const float ang = (float)s * invf;
  const float sn = sinf(ang), cs = cosf(ang);
  const size_t base = (size_t)row * 2048 + h * 64 + 2 * i;
  const float q0 = QKV[base], q1 = QKV[base + 1];
  const float k0 = QKV[base + 512], k1 = QKV[base + 513];
  const float cq = cs * sc, sq_ = sn * sc, ck = cs * isc, sk = sn * isc;
  QKV[base]       = q0 * cq - q1 * sq_;
  QKV[base + 1]   = q1 * cq + q0 * sq_;
  QKV[base + 512] = k0 * ck - k1 * sk;
  QKV[base + 513] = k1 * ck + k0 * sk;
}

// ---- naive retention attention (fp32) ------------------------------------
// bid = srow*8 + h; srow = local (b,s) row. QKV row: [Q(512) K(512) V(1024)]
// V at col 1024 + h*128 + v. Y out: row*1024 + h*128 + v
__global__ __launch_bounds__(256)
void attn_naive(const float* __restrict__ QKV, float* __restrict__ Y) {
  __shared__ float qs[64];
  __shared__ float am[256];
  const int bid = blockIdx.x;
  const int h = bid & 7;
  const int srow = bid >> 3;
  const int b = srow >> 8, s = srow & 255;
  const int tid = threadIdx.x;
  const float l32 = logf(1.0f / 32.0f), l512 = logf(1.0f / 512.0f);
  const float gamma = 1.0f - expf(l32 + (float)h * (l512 - l32) / 7.0f);
  const float lgam = logf(gamma);
  if (tid < 64)
    qs[tid] = QKV[(size_t)srow * 2048 + h * 64 + tid];
  __syncthreads();
  {
    const int m = tid;   // 0..255
    const float* kp = QKV + (size_t)(b * 256 + m) * 2048 + 512 + h * 64;
    float dot = 0.f;
    #pragma unroll 8
    for (int e = 0; e < 64; e++) dot += qs[e] * kp[e];
    const int d = s - m;
    const float dm = (d >= 0) ? expf((float)d * lgam) : 0.f;
    am[m] = dot * dm;
  }
  __syncthreads();
  if (tid < 128) {
    const int v = tid;
    const float* vp = QKV + 1024 + h * 128 + v;
    float y = 0.f;
    #pragma unroll 8
    for (int m = 0; m < 256; m++)
      y += am[m] * vp[(size_t)(b * 256 + m) * 2048];
    Y[(size_t)srow * 1024 + h * 128 + v] = y;
  }
}

// ---- group norm over 128 per (row,h), in place + affine ------------------
__global__ __launch_bounds__(256)
void gn_kernel(float* __restrict__ Y, const float* __restrict__ w,
               const float* __restrict__ bb) {
  const int wave = threadIdx.x >> 6, lane = threadIdx.x & 63;
  #pragma unroll
  for (int rep = 0; rep < 4; rep++) {
    const int grp = blockIdx.x * 16 + wave * 4 + rep;   // srow*8 + h
    const int h = grp & 7;
    float* yp = Y + (size_t)grp * 128 + lane * 2;
    const float y0 = yp[0], y1 = yp[1];
    const float s = wredf(y0 + y1);
    const float sq = wredf(y0 * y0 + y1 * y1);
    const float mean = s * (1.f / 128.f);
    const float var = fmaxf(sq * (1.f / 128.f) - mean * mean, 0.f);
    const float inv = rsqrtf(var + 1e-5f);
    const int vi = h * 128 + lane * 2;
    yp[0] = (y0 - mean) * inv * w[vi] + bb[vi];
    yp[1] = (y1 - mean) * inv * w[vi + 1] + bb[vi + 1];
  }
}

// ---- final N=1 dot (fp32) ------------------------------------------------
__global__ __launch_bounds__(256)
void head3_kernel(const float* __restrict__ X, const float* __restrict__ w,
                  const float* __restrict__ b3, float* __restrict__ out) {
  const int row = blockIdx.x * 4 + (threadIdx.x >> 6);
  const int lane = threadIdx.x & 63;
  const float* xp = X + (size_t)row * 512 + lane * 8;
  const float* wp = w + lane * 8;
  float s = 0.f;
  #pragma unroll
  for (int j = 0; j < 8; j++) s += xp[j] * wp[j];
  s = wredf(s);
  if (lane == 0) out[row] = s + b3[0];
}

// ---- naive tiled fp32 GEMM: C(MxN) = A(MxK) @ B(KxN) + epilogue ----------
// BMODE 0: B natural (KxN).  BMODE 1: QKV mapping — col<512: B=WQ[l](h,d,e);
//   col<1024: B2=WK[l]; else B3=WV[l](h,d,v)
// EPI 0: store    1: silu(acc)*aux     2: acc+aux
//     3: gelu(acc+bias)   4: acc+bias+aux   5: w0*sin(acc+b)+w1*cos(acc+b)
// (aux stride == N for all EPI that use it)
template<int EPI, int BMODE>
__global__ __launch_bounds__(256)
void gemm_f32(const float* __restrict__ A, const float* __restrict__ B,
              const float* __restrict__ B2, const float* __restrict__ B3,
              float* __restrict__ C, int N, int K,
              const float* __restrict__ bias, const float* __restrict__ aux,
              const float* __restrict__ wave2) {
  __shared__ float As[16][16];
  __shared__ float Bs[16][17];
  const int tx = threadIdx.x & 15, ty = threadIdx.x >> 4;
  const int row = blockIdx.y * 16 + ty;
  const int col = blockIdx.x * 16 + tx;
  float acc = 0.f;
  for (int kt = 0; kt < K; kt += 16) {
    As[ty][tx] = A[(size_t)row * K + kt + tx];
    const int k = kt + ty;
    float bv;
    if constexpr (BMODE == 0) {
      bv = B[(size_t)k * N + col];
    } else {
      if (col < 512)
        bv = B[((size_t)(col >> 6) * 512 + k) * 64 + (col & 63)];
      else if (col < 1024)
        bv = B2[((size_t)((col - 512) >> 6) * 512 + k) * 64 + ((col - 512) & 63)];
      else
        bv = B3[((size_t)((col - 1024) >> 7) * 512 + k) * 128 + ((col - 1024) & 127)];
    }
    Bs[ty][tx] = bv;
    __syncthreads();
    #pragma unroll
    for (int kk = 0; kk < 16; kk++) acc += As[ty][kk] * Bs[kk][tx];
    __syncthreads();
  }
  const size_t idx = (size_t)row * N + col;
  float v = acc;
  if constexpr (EPI == 0) {
    C[idx] = v;
  } else if constexpr (EPI == 1) {
    const float g = v / (1.f + expf(-v));
    C[idx] = g * aux[idx];
  } else if constexpr (EPI == 2) {
    C[idx] = v + aux[idx];
  } else if constexpr (EPI == 3) {
    v += bias[col];
    C[idx] = 0.5f * v * (1.f + erff(v * 0.70710678118654752f));
  } else if constexpr (EPI == 4) {
    C[idx] = v + bias[col] + aux[idx];
  } else if constexpr (EPI == 5) {
    v += bias[col];
    C[idx] = wave2[0] * sinf(v) + wave2[1] * cosf(v);
  }
}

// ---- launch --------------------------------------------------------------

extern "C" void kernel_launch(void* const* d_in, const int* in_sizes, int n_in,
                              void* d_out, int out_size, void* d_ws, size_t ws_size,
                              hipStream_t stream) {
  (void)in_sizes; (void)n_in; (void)out_size;
  const float* x    = (const float*)d_in[0];
  const float* t    = (const float*)d_in[1];
  const float* embW = (const float*)d_in[2];
  const float* embB = (const float*)d_in[3];
  const float* ln1w = (const float*)d_in[4];
  const float* ln1b = (const float*)d_in[5];
  const float* ln2w = (const float*)d_in[6];
  const float* ln2b = (const float*)d_in[7];
  const float* WQ   = (const float*)d_in[8];
  const float* WK   = (const float*)d_in[9];
  const float* WV   = (const float*)d_in[10];
  const float* WG   = (const float*)d_in[11];
  const float* WO   = (const float*)d_in[12];
  const float* gnw  = (const float*)d_in[13];
  const float* gnb  = (const float*)d_in[14];
  const float* f1W  = (const float*)d_in[15];
  const float* f1b  = (const float*)d_in[16];
  const float* f2W  = (const float*)d_in[17];
  const float* f2bp = (const float*)d_in[18];
  const float* h1W  = (const float*)d_in[19];
  const float* h1b  = (const float*)d_in[20];
  const float* wvw  = (const float*)d_in[21];
  const float* h2W  = (const float*)d_in[22];
  const float* h2b  = (const float*)d_in[23];
  const float* h3W  = (const float*)d_in[24];
  const float* h3b  = (const float*)d_in[25];

  // ---- choose batch-chunking so fp32 activations fit ws_size ----
  // per-row floats: Xf 512 + Xn 512 + QKV 2048 + Yb 1024 + Yr 512 = 4608
  int NC = 1;
  while (NC < 256) {
    const size_t R = 65536u / NC;
    if (R * 18432 + 4096 <= ws_size) break;
    NC <<= 1;
  }
  const int R = 65536 / NC;   // rows per chunk (multiple of 256)

  float* Xf   = (float*)d_ws;          // R x 512   residual
  float* Xn   = Xf  + (size_t)R * 512; // R x 512   LN out / H1
  float* QKVb = Xn  + (size_t)R * 512; // R x 2048  QKV; later GY in first 1024
  float* Yb   = QKVb + (size_t)R * 2048; // R x 1024 Y / mid / H2
  float* Yr   = Yb  + (size_t)R * 1024; // R x 512   Yr (fp32 residual branch)

  const dim3 blk(256);

  for (int c = 0; c < NC; c++) {
    const size_t off = (size_t)c * R;
    embed_kernel<<<dim3(R / 4), blk, 0, stream>>>(x + off, t + off, embW, embB, Xf);

    for (int l = 0; l < 4; l++) {
      ln_kernel<<<dim3(R / 4), blk, 0, stream>>>(Xf, ln1w + l * 512, ln1b + l * 512, Xn);
      // QKV = Xn @ [WQ|WK|WV][l]   (N=2048, K=512, head-mapped B)
      gemm_f32<0, 1><<<dim3(128, R / 16), blk, 0, stream>>>(
          Xn, WQ + (size_t)l * 262144, WK + (size_t)l * 262144,
          WV + (size_t)l * 524288, QKVb, 2048, 512, nullptr, nullptr, nullptr);
      xpos_kernel<<<dim3(R), blk, 0, stream>>>(QKVb);
      attn_naive<<<dim3(R * 8), blk, 0, stream>>>(QKVb, Yb);
      gn_kernel<<<dim3(R / 2), blk, 0, stream>>>(Yb, gnw + l * 1024, gnb + l * 1024);
      // GY = silu(Xn @ WG[l]) * Y   -> first R*1024 of QKVb (QKV dead)
      gemm_f32<1, 0><<<dim3(64, R / 16), blk, 0, stream>>>(
          Xn, WG + (size_t)l * 524288, nullptr, nullptr,
          QKVb, 1024, 512, nullptr, Yb, nullptr);
      // Yr = GY @ WO[l] + X
      gemm_f32<2, 0><<<dim3(32, R / 16), blk, 0, stream>>>(
          QKVb, WO + (size_t)l * 524288, nullptr, nullptr,
          Yr, 512, 1024, nullptr, Xf, nullptr);
      ln_kernel<<<dim3(R / 4), blk, 0, stream>>>(Yr, ln2w + l * 512, ln2b + l * 512, Xn);
      // mid = gelu(Xn @ f1[l] + b1)  -> Yb (Y dead)
      gemm_f32<3, 0><<<dim3(8, R / 16), blk, 0, stream>>>(
          Xn, f1W + (size_t)l * 65536, nullptr, nullptr,
          Yb, 128, 512, f1b + l * 128, nullptr, nullptr);
      // X = mid @ f2[l] + b2 + Yr
      gemm_f32<4, 0><<<dim3(32, R / 16), blk, 0, stream>>>(
          Yb, f2W + (size_t)l * 65536, nullptr, nullptr,
          Xf, 512, 128, f2bp + l * 512, Yr, nullptr);
    }

    // head
    gemm_f32<5, 0><<<dim3(32, R / 16), blk, 0, stream>>>(
        Xf, h1W, nullptr, nullptr, Xn, 512, 512, h1b, nullptr, wvw);
    gemm_f32<5, 0><<<dim3(32, R / 16), blk, 0, stream>>>(
        Xn, h2W, nullptr, nullptr, Yb, 512, 512, h2b, nullptr, wvw + 2);
    head3_kernel<<<dim3(R / 4), blk, 0, stream>>>(
        Yb, h3W, h3b, (float*)d_out + off);
  }
}